// Round 15
// baseline (191.019 us; speedup 1.0000x reference)
//
#include <hip/hip_runtime.h>
#include <cstdint>
#include <cstddef>

// Problem constants (fixed by the reference file)
#define NB   8
#define VV   4096
#define KNN  40
#define NTOT 32768
#define CAP  224   // compact within-radius list capacity per query
#define INFB 0x7F800000u
#define ONEB 0x3F800000u

// 2-D sort key: 16 x-slabs (width 0.5) x 32 y-buckets (width 0.25) over [-4,4]
__device__ __forceinline__ int slabf(float x) {
  int b = (int)floorf((x + 4.f) * 2.f);
  return b < 0 ? 0 : (b > 15 ? 15 : b);
}
__device__ __forceinline__ int ybf(float y) {
  int b = (int)floorf((y + 4.f) * 4.f);
  return b < 0 ? 0 : (b > 31 ? 31 : b);
}

// ---------------------------------------------------------------------------
// Kernel 1: coords = x@W_sp + b_sp ; feat = x@W_prop + b_prop ;
//           xW = x @ W_out[128:192,:] (into d_out) ; + (slab,y) histogram
// ---------------------------------------------------------------------------
__global__ __launch_bounds__(256) void k_prep(
    const float* __restrict__ x, const float* __restrict__ W_prop,
    const float* __restrict__ b_prop, const float* __restrict__ W_sp,
    const float* __restrict__ b_sp, const float* __restrict__ W_out,
    float* __restrict__ coords, float* __restrict__ feat,
    float* __restrict__ xW, int* __restrict__ hist)
{
  __shared__ float xt[64][64];
  const int t = threadIdx.x;
  const int row0 = blockIdx.x * 64;

  #pragma unroll
  for (int i = 0; i < 16; ++i) {
    int idx = t + i * 256;
    xt[idx >> 6][idx & 63] = x[(size_t)row0 * 64 + idx];
  }
  __syncthreads();

  {
    const int col = t & 63, rb = (t >> 6) * 16;
    float acc[16];
    #pragma unroll
    for (int i = 0; i < 16; ++i) acc[i] = b_prop[col];
    for (int k = 0; k < 64; k += 4) {
      const float w0 = W_prop[(k + 0) * 64 + col];
      const float w1 = W_prop[(k + 1) * 64 + col];
      const float w2 = W_prop[(k + 2) * 64 + col];
      const float w3 = W_prop[(k + 3) * 64 + col];
      #pragma unroll
      for (int i = 0; i < 16; ++i) {
        const float4 a4 = *(const float4*)&xt[rb + i][k];
        acc[i] += a4.x * w0 + a4.y * w1 + a4.z * w2 + a4.w * w3;
      }
    }
    #pragma unroll
    for (int i = 0; i < 16; ++i)
      feat[(size_t)(row0 + rb + i) * 64 + col] = acc[i];
  }

  {
    const int col = t & 127, who = t >> 7;
    #pragma unroll
    for (int p = 0; p < 2; ++p) {
      const int rb = who * 16 + p * 32;
      float acc[16];
      #pragma unroll
      for (int i = 0; i < 16; ++i) acc[i] = 0.f;
      for (int k = 0; k < 64; k += 4) {
        const float w0 = W_out[(size_t)(128 + k + 0) * 128 + col];
        const float w1 = W_out[(size_t)(128 + k + 1) * 128 + col];
        const float w2 = W_out[(size_t)(128 + k + 2) * 128 + col];
        const float w3 = W_out[(size_t)(128 + k + 3) * 128 + col];
        #pragma unroll
        for (int i = 0; i < 16; ++i) {
          const float4 a4 = *(const float4*)&xt[rb + i][k];
          acc[i] += a4.x * w0 + a4.y * w1 + a4.z * w2 + a4.w * w3;
        }
      }
      #pragma unroll
      for (int i = 0; i < 16; ++i)
        xW[(size_t)(row0 + rb + i) * 128 + col] = acc[i];
    }
  }

  if (t < 64) {
    float a0 = b_sp[0], a1 = b_sp[1], a2 = b_sp[2], a3 = b_sp[3];
    for (int k = 0; k < 64; ++k) {
      const float xv = xt[t][k];
      a0 += xv * W_sp[k * 4 + 0];
      a1 += xv * W_sp[k * 4 + 1];
      a2 += xv * W_sp[k * 4 + 2];
      a3 += xv * W_sp[k * 4 + 3];
    }
    ((float4*)coords)[row0 + t] = make_float4(a0, a1, a2, a3);
    const int ev = (row0 + t) >> 12;
    atomicAdd(&hist[ev * 512 + slabf(a0) * 32 + ybf(a1)], 1);
  }
}

// ---------------------------------------------------------------------------
// Kernel 1b: wide scatter into (slab,y)-sorted order; ALSO permutes the
// feature rows (featS[pos] = feat[i]) so k_knn needs no index translation.
// 64 blocks; each block locally prefix-scans its event's 512-bucket
// histogram. Blocks with (bid&7)==0 emit prefg. cursorDelta pre-zeroed.
// ---------------------------------------------------------------------------
__global__ __launch_bounds__(512) void k_scatter(
    const float* __restrict__ coords, float* __restrict__ csort,
    const float* __restrict__ feat, float* __restrict__ featS,
    unsigned short* __restrict__ perm, const int* __restrict__ hist,
    int* __restrict__ cursorDelta, unsigned short* __restrict__ prefg)
{
  __shared__ int pref[513];
  const int t = threadIdx.x;
  const int ev = blockIdx.x >> 3;
  const int i = ((blockIdx.x & 7) << 9) + t;   // 0..4095
  const int evbase = ev * VV;

  if (t < 64) {
    const int l = t;
    const int* h = hist + ev * 512 + 8 * l;
    int hv[8], s = 0;
    #pragma unroll
    for (int j = 0; j < 8; ++j) { hv[j] = h[j]; s += hv[j]; }
    int incl = s;
    #pragma unroll
    for (int off = 1; off < 64; off <<= 1) {
      const int v = __shfl_up(incl, off);
      if (l >= off) incl += v;
    }
    int run = incl - s;
    #pragma unroll
    for (int j = 0; j < 8; ++j) { pref[8 * l + j] = run; run += hv[j]; }
    if (l == 63) pref[512] = run;   // == VV
  }
  __syncthreads();

  const float4 c = ((const float4*)coords)[evbase + i];
  const int key = slabf(c.x) * 32 + ybf(c.y);
  const int pos = pref[key] + atomicAdd(&cursorDelta[ev * 512 + key], 1);
  ((float4*)csort)[evbase + pos] = c;
  perm[evbase + pos] = (unsigned short)i;

  // Permute the 64-float feature row (16 x float4).
  {
    const float4* src = (const float4*)(feat  + (size_t)(evbase + i)   * 64);
    float4*       dst = (float4*)      (featS + (size_t)(evbase + pos) * 64);
    #pragma unroll
    for (int j = 0; j < 16; ++j) dst[j] = src[j];
  }

  if ((blockIdx.x & 7) == 0) {
    prefg[ev * 513 + t] = (unsigned short)pref[t];
    if (t == 0) prefg[ev * 513 + 512] = (unsigned short)pref[512];
  }
}

// ---------------------------------------------------------------------------
// Kernel 2: per-query KNN + aggregation on (slab,y)-sorted coords AND sorted
// features: no per-entry index translation anywhere.
// ---------------------------------------------------------------------------
template <int NC>
__device__ __forceinline__ unsigned bs40(const uint2* __restrict__ list,
                                         int M, int lane) {
  unsigned dv[NC];
  #pragma unroll
  for (int j = 0; j < NC; ++j) {
    const int e = lane + j * 64;
    dv[j] = (e < M) ? list[e].x : INFB;
  }
  unsigned lo = 0, hi = ONEB;
  while (lo < hi) {
    const unsigned mid = (lo + hi) >> 1;
    int cnt = 0;
    #pragma unroll
    for (int j = 0; j < NC; ++j)
      cnt += (int)__popcll(__ballot(dv[j] <= mid));
    if (cnt >= KNN) hi = mid; else lo = mid + 1;
  }
  return hi;
}

#define AGG_CHUNK(J0, N)                                                     \
  {                                                                          \
    float fv[N], wgt[N];                                                     \
    _Pragma("unroll")                                                        \
    for (int j = 0; j < N; ++j) {                                            \
      const uint2 en = list[(J0) + j];        /* uniform ds_read_b64 */      \
      wgt[j] = __expf(-10.f * __uint_as_float(en.x));                        \
      const int ei = __builtin_amdgcn_readfirstlane((int)en.y);              \
      fv[j] = feS[(size_t)ei * 64 + lane];    /* sorted-space, no perm */    \
    }                                                                        \
    _Pragma("unroll")                                                        \
    for (int j = 0; j < N; ++j) {                                            \
      const float v = fv[j] * wgt[j];                                        \
      vmax = fmaxf(vmax, v);                                                 \
      vsum += v;                                                             \
    }                                                                        \
  }

__global__ __launch_bounds__(512, 4) void k_knn(
    const float* __restrict__ coords,           // (slab,y)-sorted per event
    const unsigned short* __restrict__ perm,    // sorted pos -> orig local
    const unsigned short* __restrict__ prefg,
    const float* __restrict__ featSorted, float* __restrict__ agg)
{
  __shared__ float4 cs[VV];            // 64 KB
  __shared__ uint2 lists[8][CAP];      // 14336 B
  __shared__ unsigned short pr[513];   // 1026 B (total ~81.4 KB -> 2 blk/CU)

  const int t = threadIdx.x, lane = t & 63;
  const int wvid = __builtin_amdgcn_readfirstlane(t) >> 6;
  const int bid0 = blockIdx.x;
  const int bid = (bid0 & 7) * 64 + (bid0 >> 3);   // XCD-bijective swizzle
  const int ev = bid >> 6;                         // 64 blocks per event
  const int slot = bid & 63;                       // 64 queries per block
  const int evbase = ev * VV;

  {
    const float4* cg = (const float4*)coords + evbase;
    for (int i = t; i < VV; i += 512) cs[i] = cg[i];
    for (int i = t; i < 513; i += 512) pr[i] = prefg[ev * 513 + i];
  }
  __syncthreads();

  uint2* list = lists[wvid];
  const float* feS = featSorted + (size_t)evbase * 64;
  const unsigned long long lmask = (1ull << lane) - 1ull;

  // Multi-segment radius scan over <=5 slabs; segments 64-aligned, starts
  // clamped to previous end (no overlap after alignment -> no double count).
  auto scanAll = [&](unsigned rbits, int q, float4 qc,
                     int slo, int shi, int yblo, int ybhi) -> int {
    int M = 0, pend = 0;
    for (int s = slo; s <= shi; ++s) {
      int alo = ((int)pr[(s << 5) + yblo]) & ~63;
      int ahi = (((int)pr[(s << 5) + ybhi + 1]) + 63) & ~63;
      alo = alo < pend ? pend : alo;
      if (ahi < alo) ahi = alo;
      pend = ahi;
      #pragma unroll 4
      for (int base = alo; base < ahi; base += 64) {
        const int c = base + lane;
        const float4 cc = cs[c];
        const float dx = qc.x - cc.x, dy = qc.y - cc.y;
        const float dz = qc.z - cc.z, dw = qc.w - cc.w;
        const float dsq = dx * dx + dy * dy + dz * dz + dw * dw;
        const bool pred = (__float_as_uint(dsq) <= rbits) && (c != q);
        const unsigned long long bm = __ballot(pred);
        if (pred) {
          const int pos = M + (int)__popcll(bm & lmask);
          if (pos < CAP)
            list[pos] = make_uint2(__float_as_uint(dsq), (unsigned)c);
        }
        M += (int)__popcll(bm);
      }
    }
    return M;
  };

  for (int qi = 0; qi < 8; ++qi) {
    const int q = slot + (qi * 8 + wvid) * 64;   // sorted-space id
    const float4 qc = cs[q];
    const int origq = (int)perm[evbase + q];     // uniform, once per query
    const int slo = slabf(qc.x - 1.f), shi = slabf(qc.x + 1.f);
    const int yblo = ybf(qc.y - 1.f),  ybhi = ybf(qc.y + 1.f);

    int M = scanAll(ONEB, q, qc, slo, shi, yblo, ybhi);
    bool ok = true;

    if (M > CAP) {
      const unsigned t0 = bs40<4>(list, CAP, lane);
      M = scanAll(t0, q, qc, slo, shi, yblo, ybhi);
      ok = (M <= CAP);
    }

    float vmax = -__builtin_inff(), vsum = 0.f;

    if (ok) {
      int Msel;
      if (M > KNN) {
        unsigned taub;
        if      (M <=  64) taub = bs40<1>(list, M, lane);
        else if (M <= 128) taub = bs40<2>(list, M, lane);
        else               taub = bs40<4>(list, M, lane);
        int S = 0;
        for (int be = 0; be < M; be += 64) {
          const int e = be + lane;
          uint2 en = make_uint2(0u, 0u);
          bool p = false;
          if (e < M) { en = list[e]; p = (en.x <= taub); }
          const unsigned long long bm = __ballot(p);
          if (p) list[S + (int)__popcll(bm & lmask)] = en;
          S += (int)__popcll(bm);
        }
        Msel = S;
      } else {
        // Pad to exactly KNN with self entries (dsq=0 -> w=1), sorted-space.
        if (lane >= M && lane < KNN)
          list[lane] = make_uint2(0u, (unsigned)q);
        Msel = KNN;
      }

      if (Msel == KNN) {
        AGG_CHUNK(0, 16)
        AGG_CHUNK(16, 16)
        AGG_CHUNK(32, 8)
      } else {
        // Tie case (Msel > 40): dynamic loop.
        #pragma unroll 4
        for (int e = 0; e < Msel; ++e) {
          const uint2 en = list[e];
          const int ei = __builtin_amdgcn_readfirstlane((int)en.y);
          const float w = __expf(-10.f * __uint_as_float(en.x));
          const float v = feS[(size_t)ei * 64 + lane] * w;
          vmax = fmaxf(vmax, v);
          vsum += v;
        }
      }
    } else {
      // Exact fallback over the segments (statistically unreachable).
      unsigned lo = 0, hi = ONEB;
      while (lo < hi) {
        const unsigned mid = (lo + hi) >> 1;
        const float fm = __uint_as_float(mid);
        int cnt = 0, pend = 0;
        for (int s = slo; s <= shi; ++s) {
          int alo = ((int)pr[(s << 5) + yblo]) & ~63;
          int ahi = (((int)pr[(s << 5) + ybhi + 1]) + 63) & ~63;
          alo = alo < pend ? pend : alo;
          if (ahi < alo) ahi = alo;
          pend = ahi;
          for (int base = alo; base < ahi; base += 64) {
            const int c = base + lane;
            const float4 cc = cs[c];
            const float dx = qc.x - cc.x, dy = qc.y - cc.y;
            const float dz = qc.z - cc.z, dw = qc.w - cc.w;
            const float dsq = dx * dx + dy * dy + dz * dz + dw * dw;
            cnt += (int)__popcll(__ballot(dsq <= fm && c != q));
          }
        }
        if (cnt >= KNN) hi = mid; else lo = mid + 1;
      }
      const float tau = __uint_as_float(hi);
      int pend = 0;
      for (int s = slo; s <= shi; ++s) {
        int alo = ((int)pr[(s << 5) + yblo]) & ~63;
        int ahi = (((int)pr[(s << 5) + ybhi + 1]) + 63) & ~63;
        alo = alo < pend ? pend : alo;
        if (ahi < alo) ahi = alo;
        pend = ahi;
        for (int c = alo; c < ahi; ++c) {
          if (c == q) continue;
          const float4 cc = cs[c];
          const float dx = qc.x - cc.x, dy = qc.y - cc.y;
          const float dz = qc.z - cc.z, dw = qc.w - cc.w;
          const float dsq = dx * dx + dy * dy + dz * dz + dw * dw;
          if (dsq <= tau) {
            const float w = __expf(-10.f * dsq);
            const float v = feS[(size_t)c * 64 + lane] * w;
            vmax = fmaxf(vmax, v);
            vsum += v;
          }
        }
      }
    }

    const int g = evbase + origq;
    agg[(size_t)g * 128 + lane]      = vmax;
    agg[(size_t)g * 128 + 64 + lane] = vsum * (1.f / 40.f);
  }
}

// ---------------------------------------------------------------------------
// Kernel 3: out = tanh(agg @ W_out[0:128,:] + xW + b_out), in place on d_out
// ---------------------------------------------------------------------------
__global__ __launch_bounds__(256) void k_out(
    const float* __restrict__ agg, const float* __restrict__ W_out,
    const float* __restrict__ b_out, float* __restrict__ out)
{
  __shared__ float at[64][128];
  const int t = threadIdx.x;
  const int row0 = blockIdx.x * 64;

  #pragma unroll
  for (int i = 0; i < 32; ++i) {
    int idx = t + i * 256;
    at[idx >> 7][idx & 127] = agg[(size_t)row0 * 128 + idx];
  }
  __syncthreads();

  const int col = t & 127, who = t >> 7;
  #pragma unroll
  for (int p = 0; p < 2; ++p) {
    const int rb = who * 16 + p * 32;
    float acc[16];
    #pragma unroll
    for (int i = 0; i < 16; ++i) acc[i] = 0.f;
    for (int k = 0; k < 128; k += 4) {
      const float w0 = W_out[(size_t)(k + 0) * 128 + col];
      const float w1 = W_out[(size_t)(k + 1) * 128 + col];
      const float w2 = W_out[(size_t)(k + 2) * 128 + col];
      const float w3 = W_out[(size_t)(k + 3) * 128 + col];
      #pragma unroll
      for (int i = 0; i < 16; ++i) {
        const float4 a4 = *(const float4*)&at[rb + i][k];
        acc[i] += a4.x * w0 + a4.y * w1 + a4.z * w2 + a4.w * w3;
      }
    }
    const float bb = b_out[col];
    #pragma unroll
    for (int i = 0; i < 16; ++i) {
      const size_t o = (size_t)(row0 + rb + i) * 128 + col;
      float v = acc[i] + bb + out[o];   // out currently holds xW
      v = fminf(15.f, fmaxf(-15.f, v));
      const float e = __expf(2.f * v);
      out[o] = (e - 1.f) / (e + 1.f);
    }
  }
}

// ---------------------------------------------------------------------------
extern "C" void kernel_launch(void* const* d_in, const int* in_sizes, int n_in,
                              void* d_out, int out_size, void* d_ws, size_t ws_size,
                              hipStream_t stream) {
  const float* x      = (const float*)d_in[0];
  const float* W_prop = (const float*)d_in[1];
  const float* b_prop = (const float*)d_in[2];
  const float* W_sp   = (const float*)d_in[3];
  const float* b_sp   = (const float*)d_in[4];
  const float* W_out  = (const float*)d_in[5];
  const float* b_out  = (const float*)d_in[6];

  float* out = (float*)d_out;
  char* ws = (char*)d_ws;
  float* coords          = (float*)(ws);                           // 512 KB
  float* csort           = (float*)(ws + (512 << 10));             // 512 KB
  float* feat            = (float*)(ws + (1 << 20));               // 8 MB
  float* featS           = (float*)(ws + (9 << 20));               // 8 MB
  float* agg             = (float*)(ws + (17 << 20));              // 16 MB
  unsigned short* perm   = (unsigned short*)(ws + (33 << 20));             // 64 KB
  unsigned short* prefg  = (unsigned short*)(ws + (33 << 20) + 65536);     // 8208 B (pad 8704)
  int* hist              = (int*)(ws + (33 << 20) + 65536 + 8704);         // 16 KB
  int* cursorDelta       = (int*)(ws + (33 << 20) + 65536 + 8704 + 16384); // 16 KB
  // total ws use: ~33.1 MB

  hipMemsetAsync(hist, 0, 32768, stream);   // zeroes hist + cursorDelta
  k_prep<<<NTOT / 64, 256, 0, stream>>>(x, W_prop, b_prop, W_sp, b_sp, W_out,
                                        coords, feat, out /* xW staged here */,
                                        hist);
  k_scatter<<<NB * 8, 512, 0, stream>>>(coords, csort, feat, featS, perm,
                                        hist, cursorDelta, prefg);
  k_knn<<<NB * (VV / 64), 512, 0, stream>>>(csort, perm, prefg, featS, agg);
  k_out<<<NTOT / 64, 256, 0, stream>>>(agg, W_out, b_out, out);
}

// Round 16
// 179.964 us; speedup vs baseline: 1.0614x; 1.0614x over previous
//
#include <hip/hip_runtime.h>
#include <cstdint>
#include <cstddef>

// Problem constants (fixed by the reference file)
#define NB   8
#define VV   4096
#define KNN  40
#define NTOT 32768
#define CAP  224   // compact within-radius list capacity per query
#define INFB 0x7F800000u
#define ONEB 0x3F800000u

// 2-D sort key: 16 x-slabs (width 0.5) x 32 y-buckets (width 0.25) over [-4,4]
__device__ __forceinline__ int slabf(float x) {
  int b = (int)floorf((x + 4.f) * 2.f);
  return b < 0 ? 0 : (b > 15 ? 15 : b);
}
__device__ __forceinline__ int ybf(float y) {
  int b = (int)floorf((y + 4.f) * 4.f);
  return b < 0 ? 0 : (b > 31 ? 31 : b);
}

// ---------------------------------------------------------------------------
// Kernel 1: coords = x@W_sp + b_sp ; feat = x@W_prop + b_prop ;
//           xW = x @ W_out[128:192,:] (into d_out) ; + (slab,y) histogram
// ---------------------------------------------------------------------------
__global__ __launch_bounds__(256) void k_prep(
    const float* __restrict__ x, const float* __restrict__ W_prop,
    const float* __restrict__ b_prop, const float* __restrict__ W_sp,
    const float* __restrict__ b_sp, const float* __restrict__ W_out,
    float* __restrict__ coords, float* __restrict__ feat,
    float* __restrict__ xW, int* __restrict__ hist)
{
  __shared__ float xt[64][64];
  const int t = threadIdx.x;
  const int row0 = blockIdx.x * 64;

  #pragma unroll
  for (int i = 0; i < 16; ++i) {
    int idx = t + i * 256;
    xt[idx >> 6][idx & 63] = x[(size_t)row0 * 64 + idx];
  }
  __syncthreads();

  {
    const int col = t & 63, rb = (t >> 6) * 16;
    float acc[16];
    #pragma unroll
    for (int i = 0; i < 16; ++i) acc[i] = b_prop[col];
    for (int k = 0; k < 64; k += 4) {
      const float w0 = W_prop[(k + 0) * 64 + col];
      const float w1 = W_prop[(k + 1) * 64 + col];
      const float w2 = W_prop[(k + 2) * 64 + col];
      const float w3 = W_prop[(k + 3) * 64 + col];
      #pragma unroll
      for (int i = 0; i < 16; ++i) {
        const float4 a4 = *(const float4*)&xt[rb + i][k];
        acc[i] += a4.x * w0 + a4.y * w1 + a4.z * w2 + a4.w * w3;
      }
    }
    #pragma unroll
    for (int i = 0; i < 16; ++i)
      feat[(size_t)(row0 + rb + i) * 64 + col] = acc[i];
  }

  {
    const int col = t & 127, who = t >> 7;
    #pragma unroll
    for (int p = 0; p < 2; ++p) {
      const int rb = who * 16 + p * 32;
      float acc[16];
      #pragma unroll
      for (int i = 0; i < 16; ++i) acc[i] = 0.f;
      for (int k = 0; k < 64; k += 4) {
        const float w0 = W_out[(size_t)(128 + k + 0) * 128 + col];
        const float w1 = W_out[(size_t)(128 + k + 1) * 128 + col];
        const float w2 = W_out[(size_t)(128 + k + 2) * 128 + col];
        const float w3 = W_out[(size_t)(128 + k + 3) * 128 + col];
        #pragma unroll
        for (int i = 0; i < 16; ++i) {
          const float4 a4 = *(const float4*)&xt[rb + i][k];
          acc[i] += a4.x * w0 + a4.y * w1 + a4.z * w2 + a4.w * w3;
        }
      }
      #pragma unroll
      for (int i = 0; i < 16; ++i)
        xW[(size_t)(row0 + rb + i) * 128 + col] = acc[i];
    }
  }

  if (t < 64) {
    float a0 = b_sp[0], a1 = b_sp[1], a2 = b_sp[2], a3 = b_sp[3];
    for (int k = 0; k < 64; ++k) {
      const float xv = xt[t][k];
      a0 += xv * W_sp[k * 4 + 0];
      a1 += xv * W_sp[k * 4 + 1];
      a2 += xv * W_sp[k * 4 + 2];
      a3 += xv * W_sp[k * 4 + 3];
    }
    ((float4*)coords)[row0 + t] = make_float4(a0, a1, a2, a3);
    const int ev = (row0 + t) >> 12;
    atomicAdd(&hist[ev * 512 + slabf(a0) * 32 + ybf(a1)], 1);
  }
}

// ---------------------------------------------------------------------------
// Kernel 1b: wide scatter into (slab,y)-sorted order. 64 blocks; each block
// locally prefix-scans its event's 512-bucket histogram (redundant, ~1us).
// Blocks with (bid&7)==0 emit prefg (513 u16). cursorDelta pre-zeroed.
// ---------------------------------------------------------------------------
__global__ __launch_bounds__(512) void k_scatter(
    const float* __restrict__ coords, float* __restrict__ csort,
    unsigned short* __restrict__ perm, const int* __restrict__ hist,
    int* __restrict__ cursorDelta, unsigned short* __restrict__ prefg)
{
  __shared__ int pref[513];
  const int t = threadIdx.x;
  const int ev = blockIdx.x >> 3;
  const int i = ((blockIdx.x & 7) << 9) + t;   // 0..4095
  const int evbase = ev * VV;

  if (t < 64) {
    const int l = t;
    const int* h = hist + ev * 512 + 8 * l;
    int hv[8], s = 0;
    #pragma unroll
    for (int j = 0; j < 8; ++j) { hv[j] = h[j]; s += hv[j]; }
    int incl = s;
    #pragma unroll
    for (int off = 1; off < 64; off <<= 1) {
      const int v = __shfl_up(incl, off);
      if (l >= off) incl += v;
    }
    int run = incl - s;
    #pragma unroll
    for (int j = 0; j < 8; ++j) { pref[8 * l + j] = run; run += hv[j]; }
    if (l == 63) pref[512] = run;   // == VV
  }
  __syncthreads();

  const float4 c = ((const float4*)coords)[evbase + i];
  const int key = slabf(c.x) * 32 + ybf(c.y);
  const int pos = pref[key] + atomicAdd(&cursorDelta[ev * 512 + key], 1);
  ((float4*)csort)[evbase + pos] = c;
  perm[evbase + pos] = (unsigned short)i;

  if ((blockIdx.x & 7) == 0) {
    prefg[ev * 513 + t] = (unsigned short)pref[t];
    if (t == 0) prefg[ev * 513 + 512] = (unsigned short)pref[512];
  }
}

// ---------------------------------------------------------------------------
// Kernel 2: per-query KNN + aggregation on (slab,y)-sorted coords, then a
// FUSED output GEMM epilogue (replaces k_out): after the query loop, cs[] is
// dead -> alias it as aggS[64][128], reload this block's 64 agg rows from L2
// and compute out = tanh(agg@W_out[0:128] + xW + b_out) in-block.
// ---------------------------------------------------------------------------
template <int NC>
__device__ __forceinline__ unsigned bs40(const uint2* __restrict__ list,
                                         int M, int lane) {
  unsigned dv[NC];
  #pragma unroll
  for (int j = 0; j < NC; ++j) {
    const int e = lane + j * 64;
    dv[j] = (e < M) ? list[e].x : INFB;
  }
  unsigned lo = 0, hi = ONEB;
  while (lo < hi) {
    const unsigned mid = (lo + hi) >> 1;
    int cnt = 0;
    #pragma unroll
    for (int j = 0; j < NC; ++j)
      cnt += (int)__popcll(__ballot(dv[j] <= mid));
    if (cnt >= KNN) hi = mid; else lo = mid + 1;
  }
  return hi;
}

#define AGG_CHUNK(J0, N)                                                     \
  {                                                                          \
    float fv[N], wgt[N];                                                     \
    _Pragma("unroll")                                                        \
    for (int j = 0; j < N; ++j) {                                            \
      const uint2 en = list[(J0) + j];        /* uniform ds_read_b64 */      \
      wgt[j] = __expf(-10.f * __uint_as_float(en.x));                        \
      const int ei = __builtin_amdgcn_readfirstlane((int)en.y);              \
      fv[j] = fe[(size_t)ei * 64 + lane];     /* coalesced 256B segment */   \
    }                                                                        \
    _Pragma("unroll")                                                        \
    for (int j = 0; j < N; ++j) {                                            \
      const float v = fv[j] * wgt[j];                                        \
      vmax = fmaxf(vmax, v);                                                 \
      vsum += v;                                                             \
    }                                                                        \
  }

__global__ __launch_bounds__(512, 4) void k_knn(
    const float* __restrict__ coords,           // (slab,y)-sorted per event
    const unsigned short* __restrict__ perm,    // sorted pos -> orig local
    const unsigned short* __restrict__ prefg,
    const float* __restrict__ feat, float* __restrict__ agg,
    const float* __restrict__ W_out, const float* __restrict__ b_out,
    float* __restrict__ out)
{
  __shared__ float4 cs[VV];            // 64 KB (aliased as aggS in epilogue)
  __shared__ uint2 lists[8][CAP];      // 14336 B
  __shared__ unsigned short pr[513];   // 1026 B
  __shared__ unsigned short origq_s[64];  // 128 B (total ~81 KB -> 2 blk/CU)

  const int t = threadIdx.x, lane = t & 63;
  const int wvid = __builtin_amdgcn_readfirstlane(t) >> 6;
  const int bid0 = blockIdx.x;
  const int bid = (bid0 & 7) * 64 + (bid0 >> 3);   // XCD-bijective swizzle
  const int ev = bid >> 6;                         // 64 blocks per event
  const int slot = bid & 63;                       // 64 queries per block
  const int evbase = ev * VV;

  {
    const float4* cg = (const float4*)coords + evbase;
    for (int i = t; i < VV; i += 512) cs[i] = cg[i];
    for (int i = t; i < 513; i += 512) pr[i] = prefg[ev * 513 + i];
  }
  __syncthreads();

  uint2* list = lists[wvid];
  const float* fe = feat + (size_t)evbase * 64;
  const unsigned long long lmask = (1ull << lane) - 1ull;

  // Multi-segment radius scan over <=5 slabs; segments 64-aligned, starts
  // clamped to previous end (no overlap after alignment -> no double count).
  auto scanAll = [&](unsigned rbits, int q, float4 qc,
                     int slo, int shi, int yblo, int ybhi) -> int {
    int M = 0, pend = 0;
    for (int s = slo; s <= shi; ++s) {
      int alo = ((int)pr[(s << 5) + yblo]) & ~63;
      int ahi = (((int)pr[(s << 5) + ybhi + 1]) + 63) & ~63;
      alo = alo < pend ? pend : alo;
      if (ahi < alo) ahi = alo;
      pend = ahi;
      #pragma unroll 4
      for (int base = alo; base < ahi; base += 64) {
        const int c = base + lane;
        const float4 cc = cs[c];
        const float dx = qc.x - cc.x, dy = qc.y - cc.y;
        const float dz = qc.z - cc.z, dw = qc.w - cc.w;
        const float dsq = dx * dx + dy * dy + dz * dz + dw * dw;
        const bool pred = (__float_as_uint(dsq) <= rbits) && (c != q);
        const unsigned long long bm = __ballot(pred);
        if (pred) {
          const int pos = M + (int)__popcll(bm & lmask);
          if (pos < CAP)
            list[pos] = make_uint2(__float_as_uint(dsq), (unsigned)c);
        }
        M += (int)__popcll(bm);
      }
    }
    return M;
  };

  for (int qi = 0; qi < 8; ++qi) {
    const int q = slot + (qi * 8 + wvid) * 64;   // sorted-space id
    const float4 qc = cs[q];
    const int origq = (int)perm[evbase + q];     // original local id
    if (lane == 0) origq_s[qi * 8 + wvid] = (unsigned short)origq;
    const int slo = slabf(qc.x - 1.f), shi = slabf(qc.x + 1.f);
    const int yblo = ybf(qc.y - 1.f),  ybhi = ybf(qc.y + 1.f);

    int M = scanAll(ONEB, q, qc, slo, shi, yblo, ybhi);
    bool ok = true;

    if (M > CAP) {
      const unsigned t0 = bs40<4>(list, CAP, lane);
      M = scanAll(t0, q, qc, slo, shi, yblo, ybhi);
      ok = (M <= CAP);
    }

    float vmax = -__builtin_inff(), vsum = 0.f;

    if (ok) {
      // Convert stored sorted-space indices -> original local indices.
      for (int be = 0; be < M; be += 64) {
        const int e = be + lane;
        if (e < M) {
          uint2 en = list[e];
          en.y = (unsigned)perm[evbase + (int)en.y];
          list[e] = en;
        }
      }

      int Msel;
      if (M > KNN) {
        unsigned taub;
        if      (M <=  64) taub = bs40<1>(list, M, lane);
        else if (M <= 128) taub = bs40<2>(list, M, lane);
        else               taub = bs40<4>(list, M, lane);
        int S = 0;
        for (int be = 0; be < M; be += 64) {
          const int e = be + lane;
          uint2 en = make_uint2(0u, 0u);
          bool p = false;
          if (e < M) { en = list[e]; p = (en.x <= taub); }
          const unsigned long long bm = __ballot(p);
          if (p) list[S + (int)__popcll(bm & lmask)] = en;
          S += (int)__popcll(bm);
        }
        Msel = S;
      } else {
        // Pad to exactly KNN with self entries (dsq=0 -> w=1), matching the
        // reference's out-of-radius self-replacement.
        if (lane >= M && lane < KNN)
          list[lane] = make_uint2(0u, (unsigned)origq);
        Msel = KNN;
      }

      if (Msel == KNN) {
        AGG_CHUNK(0, 16)
        AGG_CHUNK(16, 16)
        AGG_CHUNK(32, 8)
      } else {
        #pragma unroll 4
        for (int e = 0; e < Msel; ++e) {
          const uint2 en = list[e];
          const int ei = __builtin_amdgcn_readfirstlane((int)en.y);
          const float w = __expf(-10.f * __uint_as_float(en.x));
          const float v = fe[(size_t)ei * 64 + lane] * w;
          vmax = fmaxf(vmax, v);
          vsum += v;
        }
      }
    } else {
      // Exact fallback over the segments (statistically unreachable).
      unsigned lo = 0, hi = ONEB;
      while (lo < hi) {
        const unsigned mid = (lo + hi) >> 1;
        const float fm = __uint_as_float(mid);
        int cnt = 0, pend = 0;
        for (int s = slo; s <= shi; ++s) {
          int alo = ((int)pr[(s << 5) + yblo]) & ~63;
          int ahi = (((int)pr[(s << 5) + ybhi + 1]) + 63) & ~63;
          alo = alo < pend ? pend : alo;
          if (ahi < alo) ahi = alo;
          pend = ahi;
          for (int base = alo; base < ahi; base += 64) {
            const int c = base + lane;
            const float4 cc = cs[c];
            const float dx = qc.x - cc.x, dy = qc.y - cc.y;
            const float dz = qc.z - cc.z, dw = qc.w - cc.w;
            const float dsq = dx * dx + dy * dy + dz * dz + dw * dw;
            cnt += (int)__popcll(__ballot(dsq <= fm && c != q));
          }
        }
        if (cnt >= KNN) hi = mid; else lo = mid + 1;
      }
      const float tau = __uint_as_float(hi);
      int pend = 0;
      for (int s = slo; s <= shi; ++s) {
        int alo = ((int)pr[(s << 5) + yblo]) & ~63;
        int ahi = (((int)pr[(s << 5) + ybhi + 1]) + 63) & ~63;
        alo = alo < pend ? pend : alo;
        if (ahi < alo) ahi = alo;
        pend = ahi;
        for (int c = alo; c < ahi; ++c) {
          if (c == q) continue;
          const float4 cc = cs[c];
          const float dx = qc.x - cc.x, dy = qc.y - cc.y;
          const float dz = qc.z - cc.z, dw = qc.w - cc.w;
          const float dsq = dx * dx + dy * dy + dz * dz + dw * dw;
          if (dsq <= tau) {
            const int ei = (int)perm[evbase + c];
            const float w = __expf(-10.f * dsq);
            const float v = fe[(size_t)ei * 64 + lane] * w;
            vmax = fmaxf(vmax, v);
            vsum += v;
          }
        }
      }
    }

    const int g = evbase + origq;
    agg[(size_t)g * 128 + lane]      = vmax;
    agg[(size_t)g * 128 + 64 + lane] = vsum * (1.f / 40.f);
  }

  // ---- fused output GEMM epilogue (replaces k_out) ----
  // All waves done; agg writes drained by the barrier; cs[] is dead.
  __syncthreads();
  float* aggS = (float*)cs;            // 64 rows x 128 cols = 32 KB
  #pragma unroll
  for (int p = 0; p < 4; ++p) {
    const int idx = t + p * 512;       // float4 index in [0, 2048)
    const int row = idx >> 5, seg = idx & 31;
    const int g = evbase + (int)origq_s[row];
    ((float4*)aggS)[idx] = *(const float4*)&agg[(size_t)g * 128 + seg * 4];
  }
  __syncthreads();

  {
    const int col = t & 127, who = t >> 7;       // 4 row-groups of 16
    float acc[16];
    #pragma unroll
    for (int i = 0; i < 16; ++i) acc[i] = 0.f;
    for (int k = 0; k < 128; k += 4) {
      const float w0 = W_out[(size_t)(k + 0) * 128 + col];
      const float w1 = W_out[(size_t)(k + 1) * 128 + col];
      const float w2 = W_out[(size_t)(k + 2) * 128 + col];
      const float w3 = W_out[(size_t)(k + 3) * 128 + col];
      #pragma unroll
      for (int i = 0; i < 16; ++i) {
        const float4 a4 = *(const float4*)&aggS[(who * 16 + i) * 128 + k];
        acc[i] += a4.x * w0 + a4.y * w1 + a4.z * w2 + a4.w * w3;
      }
    }
    const float bb = b_out[col];
    #pragma unroll
    for (int i = 0; i < 16; ++i) {
      const int row = who * 16 + i;
      const size_t o = ((size_t)evbase + origq_s[row]) * 128 + col;
      float v = acc[i] + bb + out[o];  // out holds xW (staged by k_prep)
      v = fminf(15.f, fmaxf(-15.f, v)); // tanh(|15|) == 1 in fp32
      const float e = __expf(2.f * v);
      out[o] = (e - 1.f) / (e + 1.f);
    }
  }
}

// ---------------------------------------------------------------------------
extern "C" void kernel_launch(void* const* d_in, const int* in_sizes, int n_in,
                              void* d_out, int out_size, void* d_ws, size_t ws_size,
                              hipStream_t stream) {
  const float* x      = (const float*)d_in[0];
  const float* W_prop = (const float*)d_in[1];
  const float* b_prop = (const float*)d_in[2];
  const float* W_sp   = (const float*)d_in[3];
  const float* b_sp   = (const float*)d_in[4];
  const float* W_out  = (const float*)d_in[5];
  const float* b_out  = (const float*)d_in[6];

  float* out = (float*)d_out;
  char* ws = (char*)d_ws;
  float* coords          = (float*)(ws);                           // 512 KB
  float* csort           = (float*)(ws + (512 << 10));             // 512 KB
  float* feat            = (float*)(ws + (1 << 20));               // 8 MB
  float* agg             = (float*)(ws + (9 << 20));               // 16 MB
  unsigned short* perm   = (unsigned short*)(ws + (25 << 20));             // 64 KB
  unsigned short* prefg  = (unsigned short*)(ws + (25 << 20) + 65536);     // 8208 B (pad 8704)
  int* hist              = (int*)(ws + (25 << 20) + 65536 + 8704);         // 16 KB
  int* cursorDelta       = (int*)(ws + (25 << 20) + 65536 + 8704 + 16384); // 16 KB
  // total ws use: ~25.1 MB

  hipMemsetAsync(hist, 0, 32768, stream);   // zeroes hist + cursorDelta
  k_prep<<<NTOT / 64, 256, 0, stream>>>(x, W_prop, b_prop, W_sp, b_sp, W_out,
                                        coords, feat, out /* xW staged here */,
                                        hist);
  k_scatter<<<NB * 8, 512, 0, stream>>>(coords, csort, perm, hist,
                                        cursorDelta, prefg);
  k_knn<<<NB * (VV / 64), 512, 0, stream>>>(csort, perm, prefg, feat, agg,
                                            W_out, b_out, out);
}